// Round 6
// baseline (211.968 us; speedup 1.0000x reference)
//
#include <hip/hip_runtime.h>
#include <math.h>

// Problem constants (fixed by setup_inputs)
#define HD 32
#define BB 256
#define SS 4096
#define BLK 256           // threads per block (4 waves)
#define POSB 256          // positions per p1 block
#define NCH (SS / POSB)   // 16 chunks per row
#define PADW 40           // WkT row stride in bf16 (80 B = 5x16B, b128-aligned)
#define PSTRIDE 33        // floats per (b,chunk) partial: l, y[32]

typedef short bf16x8 __attribute__((ext_vector_type(8)));
typedef float f32x4 __attribute__((ext_vector_type(4)));

__device__ __forceinline__ float tanh_fast(float x) {
  float e = __builtin_amdgcn_exp2f(x * 2.8853900817779268f); // 2*log2(e)
  return 1.0f - 2.0f * __builtin_amdgcn_rcpf(e + 1.0f);
}
__device__ __forceinline__ float exp_fast(float x) {
  return __builtin_amdgcn_exp2f(x * 1.4426950408889634f);    // log2(e)
}
__device__ __forceinline__ short bf16_trunc(float x) {      // truncate to bf16
  return (short)(__float_as_uint(x) >> 16);
}
__device__ __forceinline__ float hi_part(float x) {         // fp32 with low16=0
  return __uint_as_float(__float_as_uint(x) & 0xffff0000u);
}

// Phase 1: one block per (row b, chunk of 256 positions). X@Wk on MFMA
// (bf16 hi/lo split, 3 products), A-frags straight from global (coalesced),
// Wk transposed+split in LDS (5 KB). Scores bounded -> e = exp(s), no max.
// Emits per-chunk (l, y = X^T e); ctx = (Y@Wk)/L + bk reconstructed in p2.
__global__ void __launch_bounds__(BLK, 4) bahdanau_p1(
    const float* __restrict__ lstm, const float* __restrict__ fh,
    const float* __restrict__ Wq, const float* __restrict__ bq,
    const float* __restrict__ Wk, const float* __restrict__ bk,
    const float* __restrict__ Wv, const float* __restrict__ bv,
    float* __restrict__ scores_out, float* __restrict__ partials) {
  __shared__ short sWkTh[HD * PADW];  // B^T hi: [h][k] bf16
  __shared__ short sWkTl[HD * PADW];  // B^T lo
  __shared__ float sQB[HD];           // q + bk
  __shared__ float sWv[HD];
  __shared__ float sYp[4][HD];
  __shared__ float sRedL[4];

  const int tid = threadIdx.x;
  const int b = blockIdx.x >> 4;            // / NCH
  const int chunk = blockIdx.x & (NCH - 1);
  const int base = chunk * POSB;
  const int lane = tid & 63, w = tid >> 6;
  const int col = lane & 15, quad = lane >> 4;

  // Stage Wk transposed + hi/lo split: thread t covers float4 #t of Wk
  {
    float4 w4 = ((const float4*)Wk)[tid];
    const int k = tid >> 3, h0 = (tid & 7) * 4;
    const float v[4] = {w4.x, w4.y, w4.z, w4.w};
#pragma unroll
    for (int i = 0; i < 4; i++) {
      const float hf = hi_part(v[i]);
      sWkTh[(h0 + i) * PADW + k] = bf16_trunc(v[i]);
      sWkTl[(h0 + i) * PADW + k] = bf16_trunc(v[i] - hf);
    }
  }
  // qb[h] = bq[h] + bk[h] + fh[b,:] @ Wq[:,h]
  if (tid < HD) {
    float acc = bq[tid] + bk[tid];
    const float* fhb = fh + b * HD;
#pragma unroll
    for (int j = 0; j < HD; j++) acc += fhb[j] * Wq[j * HD + tid];
    sQB[tid] = acc;
    sWv[tid] = Wv[tid];
  }
  __syncthreads();

  // B-frags: lane holds B[k=quad*8+j][n=col] = WkT[n][quad*8+j], 8 contig bf16
  bf16x8 Bh0 = *(const bf16x8*)&sWkTh[(col) * PADW + quad * 8];
  bf16x8 Bl0 = *(const bf16x8*)&sWkTl[(col) * PADW + quad * 8];
  bf16x8 Bh1 = *(const bf16x8*)&sWkTh[(16 + col) * PADW + quad * 8];
  bf16x8 Bl1 = *(const bf16x8*)&sWkTl[(16 + col) * PADW + quad * 8];
  const float qb0 = sQB[col], qb1 = sQB[16 + col];
  const float wv0 = sWv[col], wv1 = sWv[16 + col];
  const float bv0 = bv[0];

  const float* gx = lstm + ((size_t)b * SS + base + w * 64) * HD;
  float lAcc = 0.f;
  float yp[8];
#pragma unroll
  for (int j = 0; j < 8; j++) yp[j] = 0.f;

#pragma unroll
  for (int mt = 0; mt < 4; mt++) {
    // A-frag source: row m = mt*16+col, k-slice quad*8..+7 (32B) — coalesced
    const float* rp = gx + (size_t)(mt * 16 + col) * HD + quad * 8;
    const float4 xa = ((const float4*)rp)[0];
    const float4 xb = ((const float4*)rp)[1];
    const float xs[8] = {xa.x, xa.y, xa.z, xa.w, xb.x, xb.y, xb.z, xb.w};
    bf16x8 Ah, Al;
#pragma unroll
    for (int j = 0; j < 8; j++) {
      const float hf = hi_part(xs[j]);
      Ah[j] = bf16_trunc(xs[j]);
      Al[j] = bf16_trunc(xs[j] - hf);
    }
    f32x4 c0 = {0.f, 0.f, 0.f, 0.f}, c1 = {0.f, 0.f, 0.f, 0.f};
    c0 = __builtin_amdgcn_mfma_f32_16x16x32_bf16(Ah, Bh0, c0, 0, 0, 0);
    c0 = __builtin_amdgcn_mfma_f32_16x16x32_bf16(Al, Bh0, c0, 0, 0, 0);
    c0 = __builtin_amdgcn_mfma_f32_16x16x32_bf16(Ah, Bl0, c0, 0, 0, 0);
    c1 = __builtin_amdgcn_mfma_f32_16x16x32_bf16(Ah, Bh1, c1, 0, 0, 0);
    c1 = __builtin_amdgcn_mfma_f32_16x16x32_bf16(Al, Bh1, c1, 0, 0, 0);
    c1 = __builtin_amdgcn_mfma_f32_16x16x32_bf16(Ah, Bl1, c1, 0, 0, 0);

    // scores: C row = quad*4+r, col = h (this lane: h=col / 16+col)
    float esc[4];
#pragma unroll
    for (int r = 0; r < 4; r++) {
      float t = tanh_fast(qb0 + c0[r]) * wv0 + tanh_fast(qb1 + c1[r]) * wv1;
      t += __shfl_xor(t, 1, 64);
      t += __shfl_xor(t, 2, 64);
      t += __shfl_xor(t, 4, 64);
      t += __shfl_xor(t, 8, 64);   // row score replicated in quad's 16 lanes
      esc[r] = exp_fast(t + bv0);
    }
    // e for this lane's A-row m=col: from quad (col>>2), slot r=col&3
    const int srcLane = (col >> 2) * 16;
    const float g0 = __shfl(esc[0], srcLane, 64);
    const float g1 = __shfl(esc[1], srcLane, 64);
    const float g2 = __shfl(esc[2], srcLane, 64);
    const float g3 = __shfl(esc[3], srcLane, 64);
    const int rr = col & 3;
    const float e_m = (rr == 0) ? g0 : (rr == 1) ? g1 : (rr == 2) ? g2 : g3;
    if (lane < 16)
      scores_out[(size_t)b * SS + base + w * 64 + mt * 16 + lane] = e_m;
    lAcc += (lane < 16) ? e_m : 0.f;
    // y partial: x registers still live
#pragma unroll
    for (int j = 0; j < 8; j++) yp[j] = fmaf(e_m, xs[j], yp[j]);
  }

  // reduce y over the 16 cols (rows of this quad-slice)
#pragma unroll
  for (int j = 0; j < 8; j++) {
    yp[j] += __shfl_xor(yp[j], 1, 64);
    yp[j] += __shfl_xor(yp[j], 2, 64);
    yp[j] += __shfl_xor(yp[j], 4, 64);
    yp[j] += __shfl_xor(yp[j], 8, 64);
  }
  if (col == 0) {
#pragma unroll
    for (int j = 0; j < 8; j++) sYp[w][quad * 8 + j] = yp[j];
  }
#pragma unroll
  for (int off = 32; off >= 1; off >>= 1) lAcc += __shfl_xor(lAcc, off, 64);
  if (lane == 0) sRedL[w] = lAcc;
  __syncthreads();

  if (tid < HD) {
    float y = sYp[0][tid] + sYp[1][tid] + sYp[2][tid] + sYp[3][tid];
    float* p = partials + (size_t)blockIdx.x * PSTRIDE;
    p[1 + tid] = y;
    if (tid == 0) p[0] = sRedL[0] + sRedL[1] + sRedL[2] + sRedL[3];
  }
}

// Phase 2: 1024 blocks; block scales 1024 consecutive scores (float4/thread)
// of row b = blk>>2. Sub-block 0 also builds ctx = (Y@Wk)/L + bk.
__global__ void __launch_bounds__(BLK) bahdanau_p2(
    const float* __restrict__ partials, const float* __restrict__ Wk,
    const float* __restrict__ bk, float* __restrict__ ctx_out,
    float* __restrict__ scores) {
  const int blk = blockIdx.x;
  const int b = blk >> 2;
  const int tid = threadIdx.x;
  __shared__ float sY[HD];

  float L = 0.f;
#pragma unroll
  for (int c = 0; c < NCH; c++)
    L += partials[(size_t)(b * NCH + c) * PSTRIDE];
  const float invL = __builtin_amdgcn_rcpf(L);

  if ((blk & 3) == 0) {   // block-uniform branch: barrier inside is legal
    if (tid < HD) {
      float y = 0.f;
#pragma unroll
      for (int c = 0; c < NCH; c++)
        y += partials[(size_t)(b * NCH + c) * PSTRIDE + 1 + tid];
      sY[tid] = y;
    }
    __syncthreads();
    if (tid < HD) {
      float c = bk[tid] * L;
#pragma unroll
      for (int j = 0; j < HD; j++) c = fmaf(sY[j], Wk[j * HD + tid], c);
      ctx_out[b * HD + tid] = c * invL;
    }
  }

  float4* srow = (float4*)(scores + (size_t)b * SS + (blk & 3) * 1024);
  float4 s = srow[tid];
  s.x *= invL; s.y *= invL; s.z *= invL; s.w *= invL;
  srow[tid] = s;
}

extern "C" void kernel_launch(void* const* d_in, const int* in_sizes, int n_in,
                              void* d_out, int out_size, void* d_ws,
                              size_t ws_size, hipStream_t stream) {
  const float* lstm = (const float*)d_in[0];
  const float* fh   = (const float*)d_in[1];
  const float* Wq   = (const float*)d_in[2];
  const float* bq   = (const float*)d_in[3];
  const float* Wk   = (const float*)d_in[4];
  const float* bk   = (const float*)d_in[5];
  const float* Wv   = (const float*)d_in[6];
  const float* bv   = (const float*)d_in[7];

  float* out = (float*)d_out;
  float* ctx_out = out;           // context: B*H floats
  float* scores = out + BB * HD;  // att_weights region (e then normalized)
  float* partials = (float*)d_ws; // BB*NCH*PSTRIDE floats (~540 KB)

  bahdanau_p1<<<BB * NCH, BLK, 0, stream>>>(lstm, fh, Wq, bq, Wk, bk, Wv, bv,
                                            scores, partials);
  bahdanau_p2<<<BB * 4, BLK, 0, stream>>>(partials, Wk, bk, ctx_out, scores);
}

// Round 7
// 206.898 us; speedup vs baseline: 1.0245x; 1.0245x over previous
//
#include <hip/hip_runtime.h>
#include <math.h>

// Problem constants (fixed by setup_inputs)
#define HD 32
#define BB 256
#define SS 4096
#define BLK 256           // threads per block (4 waves)
#define POSB 256          // positions per p1 block
#define NCH (SS / POSB)   // 16 chunks per row
#define PADW 40           // WkT row stride in bf16 (80 B, b128-aligned)
#define PSTRIDE 33        // floats per (b,chunk) partial: l, y[32]

typedef short bf16x8 __attribute__((ext_vector_type(8)));
typedef float f32x4 __attribute__((ext_vector_type(4)));

__device__ __forceinline__ float tanh_fast(float x) {
  float e = __builtin_amdgcn_exp2f(x * 2.8853900817779268f); // 2*log2(e)
  return 1.0f - 2.0f * __builtin_amdgcn_rcpf(e + 1.0f);
}
__device__ __forceinline__ float exp_fast(float x) {
  return __builtin_amdgcn_exp2f(x * 1.4426950408889634f);    // log2(e)
}
__device__ __forceinline__ short bf16_trunc(float x) {      // truncate to bf16
  return (short)(__float_as_uint(x) >> 16);
}
__device__ __forceinline__ float hi_part(float x) {         // fp32, low16=0
  return __uint_as_float(__float_as_uint(x) & 0xffff0000u);
}

// Phase 1: one block per (row b, chunk of 256 positions). X@Wk on MFMA
// (bf16 hi/lo split, 3 products). ALL 8 global loads (8 KB/wave) are issued
// up front so the full chunk is in flight during the compute chain — this is
// the single change vs R6 (which issued 2 loads per mt step, latency-serial).
__global__ void __launch_bounds__(BLK, 4) bahdanau_p1(
    const float* __restrict__ lstm, const float* __restrict__ fh,
    const float* __restrict__ Wq, const float* __restrict__ bq,
    const float* __restrict__ Wk, const float* __restrict__ bk,
    const float* __restrict__ Wv, const float* __restrict__ bv,
    float* __restrict__ scores_out, float* __restrict__ partials) {
  __shared__ short sWkTh[HD * PADW];  // B^T hi: [h][k] bf16
  __shared__ short sWkTl[HD * PADW];  // B^T lo
  __shared__ float sQB[HD];           // q + bk
  __shared__ float sWv[HD];
  __shared__ float sYp[4][HD];
  __shared__ float sRedL[4];

  const int tid = threadIdx.x;
  const int b = blockIdx.x >> 4;            // / NCH
  const int chunk = blockIdx.x & (NCH - 1);
  const int base = chunk * POSB;
  const int lane = tid & 63, w = tid >> 6;
  const int col = lane & 15, quad = lane >> 4;

  // ---- Issue ALL lstm loads first: 8 x dwordx4 per lane, no dependent use
  const float* gx = lstm + ((size_t)b * SS + base + w * 64) * HD;
  const float* rp = gx + (size_t)col * HD + quad * 8;
  float4 xa0 = ((const float4*)(rp + 0 * 16 * HD))[0];
  float4 xb0 = ((const float4*)(rp + 0 * 16 * HD))[1];
  float4 xa1 = ((const float4*)(rp + 1 * 16 * HD))[0];
  float4 xb1 = ((const float4*)(rp + 1 * 16 * HD))[1];
  float4 xa2 = ((const float4*)(rp + 2 * 16 * HD))[0];
  float4 xb2 = ((const float4*)(rp + 2 * 16 * HD))[1];
  float4 xa3 = ((const float4*)(rp + 3 * 16 * HD))[0];
  float4 xb3 = ((const float4*)(rp + 3 * 16 * HD))[1];

  // Stage Wk transposed + hi/lo split: thread t covers float4 #t of Wk
  {
    float4 w4 = ((const float4*)Wk)[tid];
    const int k = tid >> 3, h0 = (tid & 7) * 4;
    const float v[4] = {w4.x, w4.y, w4.z, w4.w};
#pragma unroll
    for (int i = 0; i < 4; i++) {
      const float hf = hi_part(v[i]);
      sWkTh[(h0 + i) * PADW + k] = bf16_trunc(v[i]);
      sWkTl[(h0 + i) * PADW + k] = bf16_trunc(v[i] - hf);
    }
  }
  // qb[h] = bq[h] + bk[h] + fh[b,:] @ Wq[:,h]
  if (tid < HD) {
    float acc = bq[tid] + bk[tid];
    const float* fhb = fh + b * HD;
#pragma unroll
    for (int j = 0; j < HD; j++) acc += fhb[j] * Wq[j * HD + tid];
    sQB[tid] = acc;
    sWv[tid] = Wv[tid];
  }
  __syncthreads();

  // B-frags: lane holds B[k=quad*8+j][n=col] = WkT[n][quad*8+j]
  bf16x8 Bh0 = *(const bf16x8*)&sWkTh[(col) * PADW + quad * 8];
  bf16x8 Bl0 = *(const bf16x8*)&sWkTl[(col) * PADW + quad * 8];
  bf16x8 Bh1 = *(const bf16x8*)&sWkTh[(16 + col) * PADW + quad * 8];
  bf16x8 Bl1 = *(const bf16x8*)&sWkTl[(16 + col) * PADW + quad * 8];
  const float qb0 = sQB[col], qb1 = sQB[16 + col];
  const float wv0 = sWv[col], wv1 = sWv[16 + col];
  const float bv0 = bv[0];

  float lAcc = 0.f;
  float yp[8];
#pragma unroll
  for (int j = 0; j < 8; j++) yp[j] = 0.f;

#define MT_STEP(mt, XA, XB)                                                    \
  {                                                                            \
    const float xs[8] = {XA.x, XA.y, XA.z, XA.w, XB.x, XB.y, XB.z, XB.w};      \
    bf16x8 Ah, Al;                                                             \
    _Pragma("unroll") for (int j = 0; j < 8; j++) {                            \
      const float hf = hi_part(xs[j]);                                         \
      Ah[j] = bf16_trunc(xs[j]);                                               \
      Al[j] = bf16_trunc(xs[j] - hf);                                          \
    }                                                                          \
    f32x4 c0 = {0.f, 0.f, 0.f, 0.f}, c1 = {0.f, 0.f, 0.f, 0.f};                \
    c0 = __builtin_amdgcn_mfma_f32_16x16x32_bf16(Ah, Bh0, c0, 0, 0, 0);        \
    c1 = __builtin_amdgcn_mfma_f32_16x16x32_bf16(Ah, Bh1, c1, 0, 0, 0);        \
    c0 = __builtin_amdgcn_mfma_f32_16x16x32_bf16(Al, Bh0, c0, 0, 0, 0);        \
    c1 = __builtin_amdgcn_mfma_f32_16x16x32_bf16(Al, Bh1, c1, 0, 0, 0);        \
    c0 = __builtin_amdgcn_mfma_f32_16x16x32_bf16(Ah, Bl0, c0, 0, 0, 0);        \
    c1 = __builtin_amdgcn_mfma_f32_16x16x32_bf16(Ah, Bl1, c1, 0, 0, 0);        \
    float esc[4];                                                              \
    _Pragma("unroll") for (int r = 0; r < 4; r++) {                            \
      float t = tanh_fast(qb0 + c0[r]) * wv0 + tanh_fast(qb1 + c1[r]) * wv1;   \
      t += __shfl_xor(t, 1, 64);                                               \
      t += __shfl_xor(t, 2, 64);                                               \
      t += __shfl_xor(t, 4, 64);                                               \
      t += __shfl_xor(t, 8, 64);                                               \
      esc[r] = exp_fast(t + bv0);                                              \
    }                                                                          \
    const int srcLane = (col >> 2) * 16;                                       \
    const float g0 = __shfl(esc[0], srcLane, 64);                              \
    const float g1 = __shfl(esc[1], srcLane, 64);                              \
    const float g2 = __shfl(esc[2], srcLane, 64);                              \
    const float g3 = __shfl(esc[3], srcLane, 64);                              \
    const int rr = col & 3;                                                    \
    const float e_m = (rr == 0) ? g0 : (rr == 1) ? g1 : (rr == 2) ? g2 : g3;   \
    if (lane < 16)                                                             \
      scores_out[(size_t)b * SS + base + w * 64 + mt * 16 + lane] = e_m;       \
    lAcc += (lane < 16) ? e_m : 0.f;                                           \
    _Pragma("unroll") for (int j = 0; j < 8; j++)                              \
        yp[j] = fmaf(e_m, xs[j], yp[j]);                                       \
  }

  MT_STEP(0, xa0, xb0)
  MT_STEP(1, xa1, xb1)
  MT_STEP(2, xa2, xb2)
  MT_STEP(3, xa3, xb3)
#undef MT_STEP

  // reduce y over the 16 cols (rows) of this quad's k-slice
#pragma unroll
  for (int j = 0; j < 8; j++) {
    yp[j] += __shfl_xor(yp[j], 1, 64);
    yp[j] += __shfl_xor(yp[j], 2, 64);
    yp[j] += __shfl_xor(yp[j], 4, 64);
    yp[j] += __shfl_xor(yp[j], 8, 64);
  }
  if (col == 0) {
#pragma unroll
    for (int j = 0; j < 8; j++) sYp[w][quad * 8 + j] = yp[j];
  }
#pragma unroll
  for (int off = 32; off >= 1; off >>= 1) lAcc += __shfl_xor(lAcc, off, 64);
  if (lane == 0) sRedL[w] = lAcc;
  __syncthreads();

  if (tid < HD) {
    float y = sYp[0][tid] + sYp[1][tid] + sYp[2][tid] + sYp[3][tid];
    float* p = partials + (size_t)blockIdx.x * PSTRIDE;
    p[1 + tid] = y;
    if (tid == 0) p[0] = sRedL[0] + sRedL[1] + sRedL[2] + sRedL[3];
  }
}

// Phase 2: 1024 blocks; block scales 1024 consecutive scores (float4/thread)
// of row b = blk>>2. Sub-block 0 also builds ctx = (Y@Wk)/L + bk.
__global__ void __launch_bounds__(BLK) bahdanau_p2(
    const float* __restrict__ partials, const float* __restrict__ Wk,
    const float* __restrict__ bk, float* __restrict__ ctx_out,
    float* __restrict__ scores) {
  const int blk = blockIdx.x;
  const int b = blk >> 2;
  const int tid = threadIdx.x;
  __shared__ float sY[HD];

  float L = 0.f;
#pragma unroll
  for (int c = 0; c < NCH; c++)
    L += partials[(size_t)(b * NCH + c) * PSTRIDE];
  const float invL = __builtin_amdgcn_rcpf(L);

  if ((blk & 3) == 0) {   // block-uniform branch: barrier inside is legal
    if (tid < HD) {
      float y = 0.f;
#pragma unroll
      for (int c = 0; c < NCH; c++)
        y += partials[(size_t)(b * NCH + c) * PSTRIDE + 1 + tid];
      sY[tid] = y;
    }
    __syncthreads();
    if (tid < HD) {
      float c = bk[tid] * L;
#pragma unroll
      for (int j = 0; j < HD; j++) c = fmaf(sY[j], Wk[j * HD + tid], c);
      ctx_out[b * HD + tid] = c * invL;
    }
  }

  float4* srow = (float4*)(scores + (size_t)b * SS + (blk & 3) * 1024);
  float4 s = srow[tid];
  s.x *= invL; s.y *= invL; s.z *= invL; s.w *= invL;
  srow[tid] = s;
}

extern "C" void kernel_launch(void* const* d_in, const int* in_sizes, int n_in,
                              void* d_out, int out_size, void* d_ws,
                              size_t ws_size, hipStream_t stream) {
  const float* lstm = (const float*)d_in[0];
  const float* fh   = (const float*)d_in[1];
  const float* Wq   = (const float*)d_in[2];
  const float* bq   = (const float*)d_in[3];
  const float* Wk   = (const float*)d_in[4];
  const float* bk   = (const float*)d_in[5];
  const float* Wv   = (const float*)d_in[6];
  const float* bv   = (const float*)d_in[7];

  float* out = (float*)d_out;
  float* ctx_out = out;           // context: B*H floats
  float* scores = out + BB * HD;  // att_weights region (e then normalized)
  float* partials = (float*)d_ws; // BB*NCH*PSTRIDE floats (~540 KB)

  bahdanau_p1<<<BB * NCH, BLK, 0, stream>>>(lstm, fh, Wq, bq, Wk, bk, Wv, bv,
                                            scores, partials);
  bahdanau_p2<<<BB * 4, BLK, 0, stream>>>(partials, Wk, bk, ctx_out, scores);
}